// Round 2
// baseline (410.188 us; speedup 1.0000x reference)
//
#include <hip/hip_runtime.h>

// i1e(x) = exp(-|x|) * I1(x) * sign(x), Abramowitz & Stegun 9.8.3/9.8.4
// rational approximations, mirroring the JAX reference (fp32 Horner, same
// coefficients, branch point 3.75). Output dtype: float32 (reference output).

__device__ __forceinline__ float i1e_f(float x) {
    float ax = fabsf(x);

    // ---- small branch: ax <= 3.75 ----
    float ts = ax * (1.0f / 3.75f);
    ts = ts * ts;
    float ps = 0.00032411f;
    ps = ps * ts + 0.00301532f;
    ps = ps * ts + 0.02658733f;
    ps = ps * ts + 0.15084934f;
    ps = ps * ts + 0.51498869f;
    ps = ps * ts + 0.87890594f;
    ps = ps * ts + 0.5f;
    float small = ax * ps * __expf(-ax);

    // ---- large branch: ax > 3.75 ----
    float axl = fmaxf(ax, 3.75f);          // avoid div issues in unselected lane
    float tl = __fdividef(3.75f, axl);
    float pl = -0.00420059f;
    pl = pl * tl + 0.01787654f;
    pl = pl * tl + (-0.02895312f);
    pl = pl * tl + 0.02282967f;
    pl = pl * tl + (-0.01031555f);
    pl = pl * tl + 0.00163801f;
    pl = pl * tl + (-0.00362018f);
    pl = pl * tl + (-0.03988024f);
    pl = pl * tl + 0.39894228f;
    float large = pl * rsqrtf(axl);

    float r = (ax <= 3.75f) ? small : large;
    return (x < 0.0f) ? -r : r;            // I1 is odd; r==0 at x==0 anyway
}

__global__ __launch_bounds__(256) void i1e_kernel(const float* __restrict__ z,
                                                  float* __restrict__ out,
                                                  long long n) {
    long long i = ((long long)blockIdx.x * blockDim.x + threadIdx.x) * 4;
    if (i + 4 <= n) {
        float4 a = *reinterpret_cast<const float4*>(z + i);
        float4 r;
        r.x = i1e_f(a.x);
        r.y = i1e_f(a.y);
        r.z = i1e_f(a.z);
        r.w = i1e_f(a.w);
        *reinterpret_cast<float4*>(out + i) = r;
    } else {
        for (; i < n; ++i) {               // scalar tail (empty for N = 2^26)
            out[i] = i1e_f(z[i]);
        }
    }
}

extern "C" void kernel_launch(void* const* d_in, const int* in_sizes, int n_in,
                              void* d_out, int out_size, void* d_ws, size_t ws_size,
                              hipStream_t stream) {
    const float* z = (const float*)d_in[0];
    float* out = (float*)d_out;
    long long n = (long long)in_sizes[0];

    long long chunks = (n + 3) / 4;
    int block = 256;
    long long grid = (chunks + block - 1) / block;
    i1e_kernel<<<(dim3)(unsigned)grid, block, 0, stream>>>(z, out, n);
}